// Round 17
// baseline (188.944 us; speedup 1.0000x reference)
//
#include <hip/hip_runtime.h>
#include <hip/hip_bf16.h>
#include <stdint.h>

typedef __attribute__((ext_vector_type(4))) float f32x4;
typedef __attribute__((ext_vector_type(8))) short bf16x8;
typedef __attribute__((ext_vector_type(4))) unsigned short u16x4;
typedef __attribute__((ext_vector_type(4))) unsigned int u32x4;

constexpr int cB = 4, cS = 4096, cD = 1024, cH = 1024;
constexpr int cM = cB * cS;      // 16384
constexpr int cK = cD;           // 1024
constexpr int NCH = 64;          // scan chunks along S
constexpr int CLEN = cS / NCH;   // 64

__device__ __forceinline__ unsigned short f2bf(float f) {
  union { float f; uint32_t u; } v; v.f = f;
  uint32_t r = v.u + 0x7FFFu + ((v.u >> 16) & 1u);
  return (unsigned short)(r >> 16);
}
__device__ __forceinline__ float bf2f(unsigned short h) {
  union { float f; uint32_t u; } v; v.u = ((uint32_t)h) << 16;
  return v.f;
}
// packed RNE f32x2 -> bf16x2 via compiler intrinsic (x->low, y->high).
__device__ __forceinline__ uint32_t pk2(float lo, float hi) {
  __hip_bfloat162 t = __float22bfloat162_rn(make_float2(lo, hi));
  union { __hip_bfloat162 b; uint32_t u; } v; v.b = t;
  return v.u;
}

// fp32 -> bf16 round for BOTH W matrices in one launch
__global__ void roundW_kernel(const float* __restrict__ wz, const float* __restrict__ wh,
                              unsigned short* __restrict__ dst) {
  const int nb = (cH * cK) / 1024;             // 1024 blocks per matrix
  const int bidx = blockIdx.x;
  const bool second = (bidx >= nb);
  const float* src = second ? wh : wz;
  const int base = ((second ? bidx - nb : bidx) * 256 + threadIdx.x) * 4;
  f32x4 x = *(const f32x4*)(src + base);
  u16x4 h;
#pragma unroll
  for (int j = 0; j < 4; ++j) h[j] = f2bf(x[j]);
  *(u16x4*)(dst + (second ? cH * cK : 0) + base) = h;
}

// ======= fused GEMM + chunk-scan epilogue.
// R16: B dbuf + counted vmcnt + raw s_barrier. R17: A LDS tile DELETED — each
// wave loads its A fragments directly from global fp32 (layout row=fr,
// col=kk*32+fq*8, refcheck-proven via the LDS path) and cvt_pk's in-register.
// Schedule keeps ONLY A-loads outstanding at every compiler wait point, so
// conservative vmcnt(0) insertion costs nothing; B(t+1) DMAs issue between
// cvt1 and MFMA-kk1 (~500cyc before next drain). LDS 64 KiB, 2 barriers/tile.
constexpr int BM = 128, BN = 128, BK = 64;
constexpr int NT = cK / BK;   // 16

__global__ __launch_bounds__(256, 2) void gemm_kernel(
    const float* __restrict__ xf,
    const unsigned short* __restrict__ wwh,   // [Wz(1024 rows); Wh(1024 rows)]
    const float* __restrict__ bz, const float* __restrict__ bhv,
    unsigned int* __restrict__ cgbuf,
    float* __restrict__ Pb, float* __restrict__ Qb)
{
  __shared__ unsigned short Bzb[2][BN * BK];    // 32 KiB
  __shared__ unsigned short Bhb[2][BN * BK];    // 32 KiB (64 KiB total)
  const int tid  = threadIdx.x;
  const int lane = tid & 63;
  const int wv   = tid >> 6;
  const int wr   = wv >> 1, wc = wv & 1;

  // XCD-chunked mapping (R7). 1024 blocks, 128/XCD.
  const int bid = blockIdx.x;          // 0..1023
  const int xcd = bid & 7;
  const int idx = bid >> 3;            // 0..127 within XCD
  const int mt  = xcd * 16 + (idx >> 3);   // 16 mt-rows per XCD, nt-fastest
  const int nt  = idx & 7;
  const int m0 = mt * BM, n0 = nt * BN;
  const int fr = lane & 15, fq = lane >> 4;

  f32x4 accz[4][4] = {};
  f32x4 acch[4][4] = {};

  // B staging: LDS linear dest; source pre-swizzled (rule #21): col ^= (row&7)
  const int srow = tid >> 3;                              // 0..31
  const int scol = (((tid & 7) ^ (srow & 7)) << 3);       // element index

  const unsigned short* gZ = wwh + (size_t)n0 * cK;
  const unsigned short* gH = wwh + (size_t)(cH + n0) * cK;
  // per-lane A row base: row = m0 + wr*64 + fr (+ i*16)
  const float* gA = xf + (size_t)(m0 + wr * 64 + fr) * cK;

  // prologue: B(0) DMAs into buf 0
#pragma unroll
  for (int r = 0; r < 4; ++r) {
    const int ldsoff = r * 4096 + tid * 16;
    const size_t goff = (size_t)(r * 32 + srow) * cK + scol;
    __builtin_amdgcn_global_load_lds((const __attribute__((address_space(1))) void*)(gZ + goff),
      (__attribute__((address_space(3))) void*)((char*)Bzb[0] + ldsoff), 16, 0, 0);
    __builtin_amdgcn_global_load_lds((const __attribute__((address_space(1))) void*)(gH + goff),
      (__attribute__((address_space(3))) void*)((char*)Bhb[0] + ldsoff), 16, 0, 0);
  }

  for (int kt = 0; kt < NT; ++kt) {
    const int cur = kt & 1, nxt = cur ^ 1;
    const int k0 = kt * BK;
    // 1. A kk=0 fragment loads (8 x f32x4, oldest vmem after B(t))
    f32x4 a0[4], a1[4];
#pragma unroll
    for (int i = 0; i < 4; ++i) {
      const float* p = gA + (size_t)(i * 16) * cK + k0 + fq * 8;
      a0[i] = *(const f32x4*)p;
      a1[i] = *(const f32x4*)(p + 4);
    }
    // 2. drain B(t) (outstanding: B(t):8 + Akk0:8 = 16 -> keep 8 = Akk0)
    asm volatile("s_waitcnt vmcnt(8)" ::: "memory");
    // 3. barrier: B(t) visible to all waves
    asm volatile("s_barrier" ::: "memory");
    // 4. cvt kk0 (only Akk0 outstanding -> any compiler wait is harmless)
    bf16x8 fa0[4];
#pragma unroll
    for (int i = 0; i < 4; ++i) {
      union { u32x4 u; bf16x8 b; } cv;
      cv.u[0] = pk2(a0[i][0], a0[i][1]);
      cv.u[1] = pk2(a0[i][2], a0[i][3]);
      cv.u[2] = pk2(a1[i][0], a1[i][1]);
      cv.u[3] = pk2(a1[i][2], a1[i][3]);
      fa0[i] = cv.b;
    }
    // 5. A kk=1 loads (reuse reg budget)
#pragma unroll
    for (int i = 0; i < 4; ++i) {
      const float* p = gA + (size_t)(i * 16) * cK + k0 + 32 + fq * 8;
      a0[i] = *(const f32x4*)p;
      a1[i] = *(const f32x4*)(p + 4);
    }
    // 6. MFMA kk0 (B ds_reads + 32 MFMA)
    {
      bf16x8 fz[4], fh[4];
#pragma unroll
      for (int i = 0; i < 4; ++i) {
        const int br = wc * 64 + i * 16 + fr;
        const int cb = (fq * 16) ^ ((br & 7) << 4);
        fz[i] = *(const bf16x8*)((const char*)Bzb[cur] + br * 128 + cb);
        fh[i] = *(const bf16x8*)((const char*)Bhb[cur] + br * 128 + cb);
      }
#pragma unroll
      for (int i = 0; i < 4; ++i)
#pragma unroll
        for (int j = 0; j < 4; ++j) {
          accz[i][j] = __builtin_amdgcn_mfma_f32_16x16x32_bf16(fa0[i], fz[j], accz[i][j], 0, 0, 0);
          acch[i][j] = __builtin_amdgcn_mfma_f32_16x16x32_bf16(fa0[i], fh[j], acch[i][j], 0, 0, 0);
        }
    }
    // 7. cvt kk1 (only Akk1 outstanding)
    bf16x8 fa1[4];
#pragma unroll
    for (int i = 0; i < 4; ++i) {
      union { u32x4 u; bf16x8 b; } cv;
      cv.u[0] = pk2(a0[i][0], a0[i][1]);
      cv.u[1] = pk2(a0[i][2], a0[i][3]);
      cv.u[2] = pk2(a1[i][0], a1[i][1]);
      cv.u[3] = pk2(a1[i][2], a1[i][3]);
      fa1[i] = cv.b;
    }
    // 8. B(t+1) DMAs (lands under MFMA kk1 + barrier + next A issue)
    if (kt + 1 < NT) {
      const int kn = k0 + BK;
#pragma unroll
      for (int r = 0; r < 4; ++r) {
        const int ldsoff = r * 4096 + tid * 16;
        const size_t goff = (size_t)(r * 32 + srow) * cK + kn + scol;
        __builtin_amdgcn_global_load_lds((const __attribute__((address_space(1))) void*)(gZ + goff),
          (__attribute__((address_space(3))) void*)((char*)Bzb[nxt] + ldsoff), 16, 0, 0);
        __builtin_amdgcn_global_load_lds((const __attribute__((address_space(1))) void*)(gH + goff),
          (__attribute__((address_space(3))) void*)((char*)Bhb[nxt] + ldsoff), 16, 0, 0);
      }
    }
    // 9. MFMA kk1
    {
      bf16x8 fz[4], fh[4];
#pragma unroll
      for (int i = 0; i < 4; ++i) {
        const int br = wc * 64 + i * 16 + fr;
        const int cb = (64 + fq * 16) ^ ((br & 7) << 4);
        fz[i] = *(const bf16x8*)((const char*)Bzb[cur] + br * 128 + cb);
        fh[i] = *(const bf16x8*)((const char*)Bhb[cur] + br * 128 + cb);
      }
#pragma unroll
      for (int i = 0; i < 4; ++i)
#pragma unroll
        for (int j = 0; j < 4; ++j) {
          accz[i][j] = __builtin_amdgcn_mfma_f32_16x16x32_bf16(fa1[i], fz[j], accz[i][j], 0, 0, 0);
          acch[i][j] = __builtin_amdgcn_mfma_f32_16x16x32_bf16(fa1[i], fh[j], acch[i][j], 0, 0, 0);
        }
    }
    // 10. end barrier: all reads of Bb[cur] done before t+2's DMA overwrite;
    //     (next iter's DMAs target Bb[cur] only at t+2, guarded by t+1's barriers)
    asm volatile("s_barrier" ::: "memory");
  }

  // ===== epilogue: packed c/g + fast exp/rcp + in-register chunk scan.
  const int b  = mt >> 5;
  const int ch = (mt & 31) * 2 + wr;
#pragma unroll
  for (int j = 0; j < 4; ++j) {
    const int n = n0 + wc * 64 + j * 16 + fr;
    const float bz_n = bz[n];
    const float bh_n = bhv[n];
    float psg[4], qsg[4];
#pragma unroll
    for (int i = 0; i < 4; ++i) {
      float p = 1.0f, q = 0.0f;
#pragma unroll
      for (int rg = 0; rg < 4; ++rg) {
        const int m = m0 + wr * 64 + i * 16 + fq * 4 + rg;
        const float kv = accz[i][j][rg] + bz_n;
        const float av2 = acch[i][j][rg] + bh_n;
        const float c = __builtin_amdgcn_rcpf(1.0f + __expf(kv));
        const float g = (av2 >= 0.0f) ? (av2 + 0.5f)
                                      : __builtin_amdgcn_rcpf(1.0f + __expf(-av2));
        cgbuf[(size_t)m * cH + n] = pk2(c, g);   // lo=c, hi=g
        q = c * q + (1.0f - c) * g;   // compose step (c,(1-c)g) ∘ (p,q)
        p = c * p;
      }
      // cross-fq ordered compose (lanes fq*16+fr; partner masks 16,32)
      float pp = __shfl_xor(p, 16), qq = __shfl_xor(q, 16);
      if (fq & 1) { q = q + p * qq; } else { q = qq + pp * q; }
      p = p * pp;
      pp = __shfl_xor(p, 32); qq = __shfl_xor(q, 32);
      if (fq & 2) { q = q + p * qq; } else { q = qq + pp * q; }
      p = p * pp;
      psg[i] = p; qsg[i] = q;
    }
    float P = psg[0], Q = qsg[0];
#pragma unroll
    for (int i = 1; i < 4; ++i) { Q = qsg[i] + psg[i] * Q; P = psg[i] * P; }
    if (fq == 0) {
      const size_t o = ((size_t)b * NCH + ch) * cH + n;
      Pb[o] = P; Qb[o] = Q;
    }
  }
}

// ======= wave-parallel chunk-prefix: Kogge-Stone compose-scan over 64 chunks.
__global__ void scan_prefix_kernel(const float* __restrict__ h0,
                                   const float* __restrict__ Pb, const float* __restrict__ Qb,
                                   float* __restrict__ hin) {
  const int wid  = (blockIdx.x * blockDim.x + threadIdx.x) >> 6;  // 0..4095
  const int lane = threadIdx.x & 63;
  const int b = wid >> 10, h = wid & 1023;
  const size_t o = ((size_t)b * NCH + lane) * cH + h;
  float P = Pb[o], Q = Qb[o];
#pragma unroll
  for (int off = 1; off < 64; off <<= 1) {
    float Po = __shfl_up(P, off), Qo = __shfl_up(Q, off);
    if (lane >= off) { Q = P * Qo + Q; P = P * Po; }
  }
  float Pe = __shfl_up(P, 1), Qe = __shfl_up(Q, 1);
  if (lane == 0) { Pe = 1.0f; Qe = 0.0f; }
  const float x = h0[b * cH + h];
  const float h0g = (x >= 0.0f) ? (x + 0.5f) : (1.0f / (1.0f + expf(-x)));  // g(h0)
  hin[o] = Pe * h0g + Qe;
}

__global__ void scan_write_kernel(const unsigned int* __restrict__ cg,
                                  const float* __restrict__ hin, float* __restrict__ out) {
  const int bc = blockIdx.x;
  const int b = bc / NCH, ch = bc % NCH;
  const int h4 = threadIdx.x * 4;
  f32x4 hc = *(const f32x4*)(hin + ((size_t)b * NCH + ch) * cH + h4);
  size_t base = ((size_t)b * cS + (size_t)ch * CLEN) * cH + h4;
#pragma unroll 4
  for (int i = 0; i < CLEN; ++i) {
    u32x4 v = *(const u32x4*)(cg + base + (size_t)i * cH);
#pragma unroll
    for (int j = 0; j < 4; ++j) {
      const float c = bf2f((unsigned short)(v[j] & 0xFFFFu));
      const float g = bf2f((unsigned short)(v[j] >> 16));
      hc[j] = c * hc[j] + (1.0f - c) * g;
    }
    *(f32x4*)(out + base + (size_t)i * cH) = hc;
  }
  if (ch == NCH - 1) {
    *(f32x4*)(out + (size_t)cM * cH + (size_t)b * cH + h4) = hc;
  }
}

extern "C" void kernel_launch(void* const* d_in, const int* in_sizes, int n_in,
                              void* d_out, int out_size, void* d_ws, size_t ws_size,
                              hipStream_t stream) {
  const float* x   = (const float*)d_in[0];
  const float* h0  = (const float*)d_in[1];
  const float* Wz  = (const float*)d_in[2];
  const float* bz  = (const float*)d_in[3];
  const float* Wh  = (const float*)d_in[4];
  const float* bh  = (const float*)d_in[5];

  char* ws = (char*)d_ws;
  unsigned short* wwh  = (unsigned short*)(ws + (((size_t)32) << 20));  // 4 MiB
  unsigned int*   cgbuf= (unsigned int*)(ws + (((size_t)40) << 20));    // 64 MiB
  float* Pb   = (float*)(ws + (((size_t)104) << 20));                   // 1 MiB
  float* Qb   = (float*)(ws + (((size_t)105) << 20));                   // 1 MiB
  float* hin  = (float*)(ws + (((size_t)106) << 20));                   // 1 MiB
  float* out  = (float*)d_out;

  roundW_kernel<<<2 * cH * cK / 1024, 256, 0, stream>>>(Wz, Wh, wwh);
  gemm_kernel<<<(cM / BM) * (cH / BN), 256, 0, stream>>>(x, wwh, bz, bh, cgbuf, Pb, Qb);
  scan_prefix_kernel<<<cB * cH * 64 / 256, 256, 0, stream>>>(h0, Pb, Qb, hin);
  scan_write_kernel<<<cB * NCH, 256, 0, stream>>>(cgbuf, hin, out);
}

// Round 18
// 117.814 us; speedup vs baseline: 1.6037x; 1.6037x over previous
//
#include <hip/hip_runtime.h>
#include <hip/hip_bf16.h>
#include <stdint.h>

typedef __attribute__((ext_vector_type(4))) float f32x4;
typedef __attribute__((ext_vector_type(8))) short bf16x8;
typedef __attribute__((ext_vector_type(4))) unsigned short u16x4;
typedef __attribute__((ext_vector_type(4))) unsigned int u32x4;

constexpr int cB = 4, cS = 4096, cD = 1024, cH = 1024;
constexpr int cM = cB * cS;      // 16384
constexpr int cK = cD;           // 1024
constexpr int NCH = 64;          // scan chunks along S
constexpr int CLEN = cS / NCH;   // 64

__device__ __forceinline__ unsigned short f2bf(float f) {
  union { float f; uint32_t u; } v; v.f = f;
  uint32_t r = v.u + 0x7FFFu + ((v.u >> 16) & 1u);
  return (unsigned short)(r >> 16);
}
__device__ __forceinline__ float bf2f(unsigned short h) {
  union { float f; uint32_t u; } v; v.u = ((uint32_t)h) << 16;
  return v.f;
}
// packed RNE f32x2 -> bf16x2 via compiler intrinsic (x->low, y->high).
__device__ __forceinline__ uint32_t pk2(float lo, float hi) {
  __hip_bfloat162 t = __float22bfloat162_rn(make_float2(lo, hi));
  union { __hip_bfloat162 b; uint32_t u; } v; v.b = t;
  return v.u;
}

// fp32 -> bf16 round for BOTH W matrices in one launch
__global__ void roundW_kernel(const float* __restrict__ wz, const float* __restrict__ wh,
                              unsigned short* __restrict__ dst) {
  const int nb = (cH * cK) / 1024;             // 1024 blocks per matrix
  const int bidx = blockIdx.x;
  const bool second = (bidx >= nb);
  const float* src = second ? wh : wz;
  const int base = ((second ? bidx - nb : bidx) * 256 + threadIdx.x) * 4;
  f32x4 x = *(const f32x4*)(src + base);
  u16x4 h;
#pragma unroll
  for (int j = 0; j < 4; ++j) h[j] = f2bf(x[j]);
  *(u16x4*)(dst + (second ? cH * cK : 0) + base) = h;
}

// ======= fused GEMM + chunk-scan epilogue (R16 structure — best measured).
// R17 post-mortem: direct-global A fragments are uncoalesced (64 lanes x 16
// rows per load instr) -> 1.6x regression. A must stream through LDS with
// wave-contiguous global reads (Guideline 2). Reverted verbatim to R16:
// B double-buffer + counted vmcnt(8) + raw s_barrier; A fp32 reg-stage with
// cvt_pk; in-order vmcnt trick (A loads older than B(t+1) DMAs).
constexpr int BM = 128, BN = 128, BK = 64;
constexpr int NT = cK / BK;   // 16

__global__ __launch_bounds__(256, 2) void gemm_kernel(
    const float* __restrict__ xf,
    const unsigned short* __restrict__ wwh,   // [Wz(1024 rows); Wh(1024 rows)]
    const float* __restrict__ bz, const float* __restrict__ bhv,
    unsigned int* __restrict__ cgbuf,
    float* __restrict__ Pb, float* __restrict__ Qb)
{
  __shared__ unsigned short Ah[BM * BK];        // 16 KiB
  __shared__ unsigned short Bzb[2][BN * BK];    // 32 KiB
  __shared__ unsigned short Bhb[2][BN * BK];    // 32 KiB (80 KiB total)
  const int tid  = threadIdx.x;
  const int lane = tid & 63;
  const int wv   = tid >> 6;
  const int wr   = wv >> 1, wc = wv & 1;

  // XCD-chunked mapping (R7). 1024 blocks, 128/XCD.
  const int bid = blockIdx.x;          // 0..1023
  const int xcd = bid & 7;
  const int idx = bid >> 3;            // 0..127 within XCD
  const int mt  = xcd * 16 + (idx >> 3);   // 16 mt-rows per XCD, nt-fastest
  const int nt  = idx & 7;
  const int m0 = mt * BM, n0 = nt * BN;
  const int fr = lane & 15, fq = lane >> 4;

  f32x4 accz[4][4] = {};
  f32x4 acch[4][4] = {};

  // staging: LDS linear dest; source pre-swizzled (rule #21): col ^= (row&7)
  const int srow = tid >> 3;                              // 0..31
  const int scol = (((tid & 7) ^ (srow & 7)) << 3);       // element index

  const float*          gX = xf  + (size_t)m0 * cK;
  const unsigned short* gZ = wwh + (size_t)n0 * cK;
  const unsigned short* gH = wwh + (size_t)(cH + n0) * cK;

  // prologue: B(0) DMAs into buf 0 (stay in flight; drained by loop's vmcnt(8))
#pragma unroll
  for (int r = 0; r < 4; ++r) {
    const int ldsoff = r * 4096 + tid * 16;
    const size_t goff = (size_t)(r * 32 + srow) * cK + scol;
    __builtin_amdgcn_global_load_lds((const __attribute__((address_space(1))) void*)(gZ + goff),
      (__attribute__((address_space(3))) void*)((char*)Bzb[0] + ldsoff), 16, 0, 0);
    __builtin_amdgcn_global_load_lds((const __attribute__((address_space(1))) void*)(gH + goff),
      (__attribute__((address_space(3))) void*)((char*)Bhb[0] + ldsoff), 16, 0, 0);
  }

  for (int kt = 0; kt < NT; ++kt) {
    const int cur = kt & 1, nxt = cur ^ 1;
    const int k0 = kt * BK;
    // 1. ALL A fp32 loads first (must be older than B(t+1) for the vmcnt trick)
    f32x4 av[8];
#pragma unroll
    for (int r = 0; r < 4; ++r) {
      const size_t goff = (size_t)(r * 32 + srow) * cK + k0 + scol;
      av[2 * r]     = *(const f32x4*)(gX + goff);
      av[2 * r + 1] = *(const f32x4*)(gX + goff + 4);
    }
    // 2. B(t+1) DMAs into the other buffer
    if (kt + 1 < NT) {
      const int kn = k0 + BK;
#pragma unroll
      for (int r = 0; r < 4; ++r) {
        const int ldsoff = r * 4096 + tid * 16;
        const size_t goff = (size_t)(r * 32 + srow) * cK + kn + scol;
        __builtin_amdgcn_global_load_lds((const __attribute__((address_space(1))) void*)(gZ + goff),
          (__attribute__((address_space(3))) void*)((char*)Bzb[nxt] + ldsoff), 16, 0, 0);
        __builtin_amdgcn_global_load_lds((const __attribute__((address_space(1))) void*)(gH + goff),
          (__attribute__((address_space(3))) void*)((char*)Bhb[nxt] + ldsoff), 16, 0, 0);
      }
    }
    // 3. drain own A loads + own B(t); leave B(t+1)'s 8 in flight (in-order)
    asm volatile("s_waitcnt vmcnt(8)" ::: "memory");
    // 4. cvt + ds_write A(t)
#pragma unroll
    for (int r = 0; r < 4; ++r) {
      u32x4 apk;
      apk[0] = pk2(av[2 * r][0], av[2 * r][1]);
      apk[1] = pk2(av[2 * r][2], av[2 * r][3]);
      apk[2] = pk2(av[2 * r + 1][0], av[2 * r + 1][1]);
      apk[3] = pk2(av[2 * r + 1][2], av[2 * r + 1][3]);
      *(u32x4*)((char*)Ah + r * 4096 + tid * 16) = apk;
    }
    // 5. barrier WITHOUT vmcnt0: all waves past their vmcnt(8) => B(t) landed;
    //    lgkmcnt(0) => ds_writes visible.
    asm volatile("s_waitcnt lgkmcnt(0)\n\ts_barrier" ::: "memory");
    // 6. compute tile t
#pragma unroll
    for (int kk = 0; kk < BK / 32; ++kk) {
      bf16x8 fa[4], fz[4], fh[4];
#pragma unroll
      for (int i = 0; i < 4; ++i) {
        const int ar = wr * 64 + i * 16 + fr;
        const int ca = (kk * 64 + fq * 16) ^ ((ar & 7) << 4);   // swizzled read (bytes)
        fa[i] = *(const bf16x8*)((const char*)Ah + ar * 128 + ca);
        const int br = wc * 64 + i * 16 + fr;
        const int cb = (kk * 64 + fq * 16) ^ ((br & 7) << 4);
        fz[i] = *(const bf16x8*)((const char*)Bzb[cur] + br * 128 + cb);
        fh[i] = *(const bf16x8*)((const char*)Bhb[cur] + br * 128 + cb);
      }
#pragma unroll
      for (int i = 0; i < 4; ++i)
#pragma unroll
        for (int j = 0; j < 4; ++j) {
          accz[i][j] = __builtin_amdgcn_mfma_f32_16x16x32_bf16(fa[i], fz[j], accz[i][j], 0, 0, 0);
          acch[i][j] = __builtin_amdgcn_mfma_f32_16x16x32_bf16(fa[i], fh[j], acch[i][j], 0, 0, 0);
        }
    }
    // 7. end-of-tile barrier: all reads of Ah/Bb[cur] complete (data-dep)
    //    before next iter overwrites Ah / DMA-writes Bb[cur].
    asm volatile("s_barrier" ::: "memory");
  }

  // ===== epilogue: packed c/g + fast exp/rcp + in-register chunk scan.
  const int b  = mt >> 5;
  const int ch = (mt & 31) * 2 + wr;
#pragma unroll
  for (int j = 0; j < 4; ++j) {
    const int n = n0 + wc * 64 + j * 16 + fr;
    const float bz_n = bz[n];
    const float bh_n = bhv[n];
    float psg[4], qsg[4];
#pragma unroll
    for (int i = 0; i < 4; ++i) {
      float p = 1.0f, q = 0.0f;
#pragma unroll
      for (int rg = 0; rg < 4; ++rg) {
        const int m = m0 + wr * 64 + i * 16 + fq * 4 + rg;
        const float kv = accz[i][j][rg] + bz_n;
        const float av2 = acch[i][j][rg] + bh_n;
        const float c = __builtin_amdgcn_rcpf(1.0f + __expf(kv));
        const float g = (av2 >= 0.0f) ? (av2 + 0.5f)
                                      : __builtin_amdgcn_rcpf(1.0f + __expf(-av2));
        cgbuf[(size_t)m * cH + n] = pk2(c, g);   // lo=c, hi=g
        q = c * q + (1.0f - c) * g;   // compose step (c,(1-c)g) ∘ (p,q)
        p = c * p;
      }
      // cross-fq ordered compose (lanes fq*16+fr; partner masks 16,32)
      float pp = __shfl_xor(p, 16), qq = __shfl_xor(q, 16);
      if (fq & 1) { q = q + p * qq; } else { q = qq + pp * q; }
      p = p * pp;
      pp = __shfl_xor(p, 32); qq = __shfl_xor(q, 32);
      if (fq & 2) { q = q + p * qq; } else { q = qq + pp * q; }
      p = p * pp;
      psg[i] = p; qsg[i] = q;
    }
    float P = psg[0], Q = qsg[0];
#pragma unroll
    for (int i = 1; i < 4; ++i) { Q = qsg[i] + psg[i] * Q; P = psg[i] * P; }
    if (fq == 0) {
      const size_t o = ((size_t)b * NCH + ch) * cH + n;
      Pb[o] = P; Qb[o] = Q;
    }
  }
}

// ======= wave-parallel chunk-prefix: Kogge-Stone compose-scan over 64 chunks.
__global__ void scan_prefix_kernel(const float* __restrict__ h0,
                                   const float* __restrict__ Pb, const float* __restrict__ Qb,
                                   float* __restrict__ hin) {
  const int wid  = (blockIdx.x * blockDim.x + threadIdx.x) >> 6;  // 0..4095
  const int lane = threadIdx.x & 63;
  const int b = wid >> 10, h = wid & 1023;
  const size_t o = ((size_t)b * NCH + lane) * cH + h;
  float P = Pb[o], Q = Qb[o];
#pragma unroll
  for (int off = 1; off < 64; off <<= 1) {
    float Po = __shfl_up(P, off), Qo = __shfl_up(Q, off);
    if (lane >= off) { Q = P * Qo + Q; P = P * Po; }
  }
  float Pe = __shfl_up(P, 1), Qe = __shfl_up(Q, 1);
  if (lane == 0) { Pe = 1.0f; Qe = 0.0f; }
  const float x = h0[b * cH + h];
  const float h0g = (x >= 0.0f) ? (x + 0.5f) : (1.0f / (1.0f + expf(-x)));  // g(h0)
  hin[o] = Pe * h0g + Qe;
}

__global__ void scan_write_kernel(const unsigned int* __restrict__ cg,
                                  const float* __restrict__ hin, float* __restrict__ out) {
  const int bc = blockIdx.x;
  const int b = bc / NCH, ch = bc % NCH;
  const int h4 = threadIdx.x * 4;
  f32x4 hc = *(const f32x4*)(hin + ((size_t)b * NCH + ch) * cH + h4);
  size_t base = ((size_t)b * cS + (size_t)ch * CLEN) * cH + h4;
#pragma unroll 4
  for (int i = 0; i < CLEN; ++i) {
    u32x4 v = *(const u32x4*)(cg + base + (size_t)i * cH);
#pragma unroll
    for (int j = 0; j < 4; ++j) {
      const float c = bf2f((unsigned short)(v[j] & 0xFFFFu));
      const float g = bf2f((unsigned short)(v[j] >> 16));
      hc[j] = c * hc[j] + (1.0f - c) * g;
    }
    *(f32x4*)(out + base + (size_t)i * cH) = hc;
  }
  if (ch == NCH - 1) {
    *(f32x4*)(out + (size_t)cM * cH + (size_t)b * cH + h4) = hc;
  }
}

extern "C" void kernel_launch(void* const* d_in, const int* in_sizes, int n_in,
                              void* d_out, int out_size, void* d_ws, size_t ws_size,
                              hipStream_t stream) {
  const float* x   = (const float*)d_in[0];
  const float* h0  = (const float*)d_in[1];
  const float* Wz  = (const float*)d_in[2];
  const float* bz  = (const float*)d_in[3];
  const float* Wh  = (const float*)d_in[4];
  const float* bh  = (const float*)d_in[5];

  char* ws = (char*)d_ws;
  unsigned short* wwh  = (unsigned short*)(ws + (((size_t)32) << 20));  // 4 MiB
  unsigned int*   cgbuf= (unsigned int*)(ws + (((size_t)40) << 20));    // 64 MiB
  float* Pb   = (float*)(ws + (((size_t)104) << 20));                   // 1 MiB
  float* Qb   = (float*)(ws + (((size_t)105) << 20));                   // 1 MiB
  float* hin  = (float*)(ws + (((size_t)106) << 20));                   // 1 MiB
  float* out  = (float*)d_out;

  roundW_kernel<<<2 * cH * cK / 1024, 256, 0, stream>>>(Wz, Wh, wwh);
  gemm_kernel<<<(cM / BM) * (cH / BN), 256, 0, stream>>>(x, wwh, bz, bh, cgbuf, Pb, Qb);
  scan_prefix_kernel<<<cB * cH * 64 / 256, 256, 0, stream>>>(h0, Pb, Qb, hin);
  scan_write_kernel<<<cB * NCH, 256, 0, stream>>>(cgbuf, hin, out);
}